// Round 6
// baseline (201.788 us; speedup 1.0000x reference)
//
#include <hip/hip_runtime.h>
#include <math.h>

constexpr int B = 16, S = 512, D = 1024, H = 16, DH = 64;
constexpr int BH = B * H;        // 256

typedef short bf16x8 __attribute__((ext_vector_type(8)));
typedef float f32x4  __attribute__((ext_vector_type(4)));

__device__ __forceinline__ unsigned short f2bf(float f) {
    unsigned u = __float_as_uint(f);
    u += 0x7fff + ((u >> 16) & 1);   // RNE
    return (unsigned short)(u >> 16);
}

// ---------------------------------------------------------------------------
// Merged convert kernel.
//  blocks [0, 8192):      x fp32 [B*S][D] -> bf16 xb
//  blocks [8192, 8960):   W [3][H][D][DH] fp32 -> WbT [3][H][DH][D] bf16
// ---------------------------------------------------------------------------
__global__ __launch_bounds__(256) void convert_xw(
    const float* __restrict__ x,
    const float* __restrict__ Wq, const float* __restrict__ Wk,
    const float* __restrict__ Wv,
    unsigned short* __restrict__ xb, unsigned short* __restrict__ WbT)
{
    __shared__ float tile[64][65];
    const int t = threadIdx.x;
    if (blockIdx.x < 8192) {
        int i = blockIdx.x * 256 + t;
        float4 v = ((const float4*)x)[i];
        ushort4 o;
        o.x = f2bf(v.x); o.y = f2bf(v.y); o.z = f2bf(v.z); o.w = f2bf(v.w);
        ((ushort4*)xb)[i] = o;
        return;
    }
    const int idx = blockIdx.x - 8192;          // [0, 768)
    const int d0 = (idx & 15) * 64;
    const int h = (idx >> 4) & 15;
    const int m = idx >> 8;
    const float* W = ((m == 0) ? Wq : (m == 1) ? Wk : Wv) + (size_t)h * D * DH;
    {
        int e = t & 63, dr = t >> 6;
        #pragma unroll
        for (int i = 0; i < 16; ++i) {
            int d = dr * 16 + i;
            tile[d][e] = W[(size_t)(d0 + d) * DH + e];
        }
    }
    __syncthreads();
    {
        int d = t & 63, er = t >> 6;
        unsigned short* out = WbT + (size_t)(m * H + h) * DH * D;
        #pragma unroll
        for (int i = 0; i < 16; ++i) {
            int e = er * 16 + i;
            out[(size_t)e * D + d0 + d] = f2bf(tile[d][e]);
        }
    }
}

// ---------------------------------------------------------------------------
// Fused QKV projection: C[8192][3072] = xb . WbT^T, 128x128 block tile,
// 4 waves in 2x2, each 64x64 (4x4 MFMA 16x16x32 bf16), BK=64, 32 KB LDS.
// m in {0,1} (q,k): OPERAND-SWAPPED mfma(b,a) -> lane's 4 regs = 4 consecutive
//   e-cols -> packed ushort4 row-major stores (16 x 8B per thread).
// m==2 (v): natural mfma(a,b) -> 4 regs = 4 consecutive srows -> transposed
//   [bh][DH][S] ushort4 stores.
// q scaled by (1/sqrt(D))*log2e.
// ---------------------------------------------------------------------------
__global__ __launch_bounds__(256) void qkv_gemm(
    const unsigned short* __restrict__ xb,
    const unsigned short* __restrict__ WbT,
    unsigned short* __restrict__ qkvb)
{
    __shared__ unsigned short As[128 * 64];   // 16 KB, swizzled g^(row&7)
    __shared__ unsigned short Bs[128 * 64];   // 16 KB

    const int t = threadIdx.x;
    const int w = t >> 6;
    const int wr = w >> 1, wc = w & 1;
    const int L = t & 63;
    const int lane15 = L & 15;
    const int quad = L >> 4;
    const int lrow8 = L >> 3;
    const int lg = L & 7;

    const int r0 = blockIdx.x * 128;   // global row (b*S+s)
    const int n0 = blockIdx.y * 128;   // global col in [0, 3072)
    const int m  = n0 >> 10;           // uniform per block

    f32x4 acc[4][4] = {};

    if (m == 2) {
        for (int k0 = 0; k0 < D; k0 += 64) {
            #pragma unroll
            for (int i = 0; i < 4; ++i) {
                int c = w * 4 + i;
                int r = c * 8 + lrow8;
                int gg = lg ^ (r & 7);
                const unsigned short* gp = xb + (size_t)(r0 + r) * D + k0 + gg * 8;
                __builtin_amdgcn_global_load_lds(
                    (const __attribute__((address_space(1))) void*)gp,
                    (__attribute__((address_space(3))) void*)(As + c * 512),
                    16, 0, 0);
                const unsigned short* gq = WbT + (size_t)(n0 + r) * D + k0 + gg * 8;
                __builtin_amdgcn_global_load_lds(
                    (const __attribute__((address_space(1))) void*)gq,
                    (__attribute__((address_space(3))) void*)(Bs + c * 512),
                    16, 0, 0);
            }
            __syncthreads();

            #pragma unroll
            for (int ks = 0; ks < 2; ++ks) {
                int gk = ks * 4 + quad;
                bf16x8 a[4], bb[4];
                #pragma unroll
                for (int rt = 0; rt < 4; ++rt) {
                    int ml = wr * 64 + rt * 16 + lane15;
                    a[rt] = *(const bf16x8*)(As + ml * 64 + ((gk ^ (ml & 7)) * 8));
                }
                #pragma unroll
                for (int ct = 0; ct < 4; ++ct) {
                    int nl = wc * 64 + ct * 16 + lane15;
                    bb[ct] = *(const bf16x8*)(Bs + nl * 64 + ((gk ^ (nl & 7)) * 8));
                }
                #pragma unroll
                for (int rt = 0; rt < 4; ++rt)
                    #pragma unroll
                    for (int ct = 0; ct < 4; ++ct)
                        acc[rt][ct] = __builtin_amdgcn_mfma_f32_16x16x32_bf16(
                            a[rt], bb[ct], acc[rt][ct], 0, 0, 0);
            }
            __syncthreads();
        }
    } else {
        for (int k0 = 0; k0 < D; k0 += 64) {
            #pragma unroll
            for (int i = 0; i < 4; ++i) {
                int c = w * 4 + i;
                int r = c * 8 + lrow8;
                int gg = lg ^ (r & 7);
                const unsigned short* gp = xb + (size_t)(r0 + r) * D + k0 + gg * 8;
                __builtin_amdgcn_global_load_lds(
                    (const __attribute__((address_space(1))) void*)gp,
                    (__attribute__((address_space(3))) void*)(As + c * 512),
                    16, 0, 0);
                const unsigned short* gq = WbT + (size_t)(n0 + r) * D + k0 + gg * 8;
                __builtin_amdgcn_global_load_lds(
                    (const __attribute__((address_space(1))) void*)gq,
                    (__attribute__((address_space(3))) void*)(Bs + c * 512),
                    16, 0, 0);
            }
            __syncthreads();

            #pragma unroll
            for (int ks = 0; ks < 2; ++ks) {
                int gk = ks * 4 + quad;
                bf16x8 a[4], bb[4];
                #pragma unroll
                for (int rt = 0; rt < 4; ++rt) {
                    int ml = wr * 64 + rt * 16 + lane15;
                    a[rt] = *(const bf16x8*)(As + ml * 64 + ((gk ^ (ml & 7)) * 8));
                }
                #pragma unroll
                for (int ct = 0; ct < 4; ++ct) {
                    int nl = wc * 64 + ct * 16 + lane15;
                    bb[ct] = *(const bf16x8*)(Bs + nl * 64 + ((gk ^ (nl & 7)) * 8));
                }
                // swapped: acc[rt][ct] holds C^T block (rows=e, cols=s)
                #pragma unroll
                for (int rt = 0; rt < 4; ++rt)
                    #pragma unroll
                    for (int ct = 0; ct < 4; ++ct)
                        acc[rt][ct] = __builtin_amdgcn_mfma_f32_16x16x32_bf16(
                            bb[ct], a[rt], acc[rt][ct], 0, 0, 0);
            }
            __syncthreads();
        }
    }

    const int h  = ((n0 >> 6) + wc) & 15;    // one head per wave
    const int bb_ = r0 >> 9;                 // batch
    const int s0 = (r0 & 511) + wr * 64;

    if (m == 2) {
        unsigned short* outv = qkvb + ((size_t)(2 * BH) + (bb_ * H + h)) * (size_t)(S * DH);
        #pragma unroll
        for (int rt = 0; rt < 4; ++rt) {
            int srow = s0 + rt * 16 + quad * 4;
            #pragma unroll
            for (int ct = 0; ct < 4; ++ct) {
                int e = ct * 16 + lane15;
                ushort4 pk;
                pk.x = f2bf(acc[rt][ct][0]);
                pk.y = f2bf(acc[rt][ct][1]);
                pk.z = f2bf(acc[rt][ct][2]);
                pk.w = f2bf(acc[rt][ct][3]);
                *(ushort4*)(outv + (size_t)e * S + srow) = pk;
            }
        }
    } else {
        // C^T: lane15 -> s-slot, quad*4+reg -> e-slot. Row-major ushort4 stores.
        const float sc = (m == 0) ? 0.04508422002778011f : 1.0f; // (1/32)*log2e
        unsigned short* out = qkvb + ((size_t)m * BH + (bb_ * H + h)) * (size_t)(S * DH);
        #pragma unroll
        for (int rt = 0; rt < 4; ++rt) {
            int srow = s0 + rt * 16 + lane15;
            #pragma unroll
            for (int ct = 0; ct < 4; ++ct) {
                int e0 = ct * 16 + quad * 4;
                ushort4 pk;
                pk.x = f2bf(acc[rt][ct][0] * sc);
                pk.y = f2bf(acc[rt][ct][1] * sc);
                pk.z = f2bf(acc[rt][ct][2] * sc);
                pk.w = f2bf(acc[rt][ct][3] * sc);
                *(ushort4*)(out + (size_t)srow * DH + e0) = pk;
            }
        }
    }
}

// ---------------------------------------------------------------------------
// Flash attention v2 (unchanged from round 5): S^T = K.Q^T with key-permuted
// Ks staging so exp2'd C-registers pack IN-LANE into the PV B-fragment.
//   g(r) = r[5]*32 | r[3:2]*8 | r[4]*4 | r[1:0]
// Per-lane row sums, quad-reduce once. O^T -> float4 stores.
// Grid (S/128, B*H), 4 waves; wave owns 32 q-rows. K-tile 64. LDS 32 KB.
// ---------------------------------------------------------------------------
__global__ __launch_bounds__(256) void attn_mfma(
    const unsigned short* __restrict__ qkvb, float* __restrict__ out)
{
    __shared__ unsigned short Qs[128 * 64];   // 16 KB
    __shared__ unsigned short Ks[64 * 64];    // 8 KB  (key rows permuted by g)
    __shared__ unsigned short Vt[64 * 64];    // 8 KB  rows = dh, cols = key

    const int t = threadIdx.x;
    const int w = t >> 6;
    const int L = t & 63;
    const int lane15 = L & 15;
    const int quad = L >> 4;
    const int lrow8 = L >> 3;
    const int lg = L & 7;
    const int qr0 = blockIdx.x * 128;
    const int bh = blockIdx.y;
    const int b = bh >> 4, h = bh & 15;

    const unsigned short* qb = qkvb + (size_t)bh * S * DH;
    const unsigned short* kb = qkvb + (size_t)(BH + bh) * S * DH;
    const unsigned short* vt = qkvb + (size_t)(2 * BH + bh) * S * DH; // [64][512]

    #pragma unroll
    for (int i = 0; i < 4; ++i) {
        int base = w * 32 + i * 8;
        int r = base + lrow8;
        int gg = lg ^ (r & 7);
        const unsigned short* gp = qb + (size_t)(qr0 + r) * DH + gg * 8;
        __builtin_amdgcn_global_load_lds(
            (const __attribute__((address_space(1))) void*)gp,
            (__attribute__((address_space(3))) void*)(Qs + base * 64),
            16, 0, 0);
    }

    f32x4 o[2][4] = {};                  // rows = dh-slot, col = qrow(lane15)
    float plsum[2] = {0.f, 0.f};
    bf16x8 qf[2][2];

    for (int kt = 0; kt < S; kt += 64) {
        #pragma unroll
        for (int i = 0; i < 2; ++i) {
            int base = (w * 2 + i) * 8;
            int r = base + lrow8;                       // LDS row 0..63
            int gr = (r & 32) | ((r & 12) << 1) | ((r & 16) >> 2) | (r & 3);
            int gg = lg ^ (r & 7);
            const unsigned short* gpk = kb + (size_t)(kt + gr) * DH + gg * 8;
            __builtin_amdgcn_global_load_lds(
                (const __attribute__((address_space(1))) void*)gpk,
                (__attribute__((address_space(3))) void*)(Ks + base * 64),
                16, 0, 0);
            const unsigned short* gpv = vt + (size_t)r * S + kt + gg * 8;
            __builtin_amdgcn_global_load_lds(
                (const __attribute__((address_space(1))) void*)gpv,
                (__attribute__((address_space(3))) void*)(Vt + base * 64),
                16, 0, 0);
        }
        __syncthreads();

        if (kt == 0) {
            #pragma unroll
            for (int mt = 0; mt < 2; ++mt)
                #pragma unroll
                for (int ks = 0; ks < 2; ++ks) {
                    int ml = w * 32 + mt * 16 + lane15;
                    int gk = ks * 4 + quad;
                    qf[mt][ks] = *(const bf16x8*)(Qs + ml * 64 + ((gk ^ (lane15 & 7)) * 8));
                }
        }

        // ---- S^T = K . Q^T ----
        f32x4 st[2][4] = {};
        #pragma unroll
        for (int ks = 0; ks < 2; ++ks) {
            int gk = ks * 4 + quad;
            bf16x8 kf[4];
            #pragma unroll
            for (int ct = 0; ct < 4; ++ct) {
                int kr = ct * 16 + lane15;
                kf[ct] = *(const bf16x8*)(Ks + kr * 64 + ((gk ^ (lane15 & 7)) * 8));
            }
            #pragma unroll
            for (int mt = 0; mt < 2; ++mt)
                #pragma unroll
                for (int ct = 0; ct < 4; ++ct)
                    st[mt][ct] = __builtin_amdgcn_mfma_f32_16x16x32_bf16(
                        kf[ct], qf[mt][ks], st[mt][ct], 0, 0, 0);
        }

        // ---- p = exp2(s); pack in-lane into PV B-fragments ----
        bf16x8 pB[2][2];
        #pragma unroll
        for (int mt = 0; mt < 2; ++mt) {
            float rs = 0.f;
            #pragma unroll
            for (int ct = 0; ct < 4; ++ct) {
                float p0 = exp2f(st[mt][ct][0]);
                float p1 = exp2f(st[mt][ct][1]);
                float p2 = exp2f(st[mt][ct][2]);
                float p3 = exp2f(st[mt][ct][3]);
                rs += (p0 + p1) + (p2 + p3);
                int hi = (ct & 1) * 4;
                pB[mt][ct >> 1][hi + 0] = (short)f2bf(p0);
                pB[mt][ct >> 1][hi + 1] = (short)f2bf(p1);
                pB[mt][ct >> 1][hi + 2] = (short)f2bf(p2);
                pB[mt][ct >> 1][hi + 3] = (short)f2bf(p3);
            }
            plsum[mt] += rs;
        }

        // ---- O^T += V^T . P^T ----
        #pragma unroll
        for (int ks = 0; ks < 2; ++ks) {
            int gk = ks * 4 + quad;
            bf16x8 vf[4];
            #pragma unroll
            for (int nt = 0; nt < 4; ++nt) {
                int dh = nt * 16 + lane15;
                vf[nt] = *(const bf16x8*)(Vt + dh * 64 + ((gk ^ (lane15 & 7)) * 8));
            }
            #pragma unroll
            for (int mt = 0; mt < 2; ++mt)
                #pragma unroll
                for (int nt = 0; nt < 4; ++nt)
                    o[mt][nt] = __builtin_amdgcn_mfma_f32_16x16x32_bf16(
                        vf[nt], pB[mt][ks], o[mt][nt], 0, 0, 0);
        }
        __syncthreads();
    }

    #pragma unroll
    for (int mt = 0; mt < 2; ++mt) {
        float l = plsum[mt];
        l += __shfl_xor(l, 16, 64);
        l += __shfl_xor(l, 32, 64);
        float inv = 1.0f / l;
        int srow = qr0 + w * 32 + mt * 16 + lane15;
        float* op = out + (size_t)(b * S + srow) * D + h * DH;
        #pragma unroll
        for (int nt = 0; nt < 4; ++nt) {
            float4 v;
            v.x = o[mt][nt][0] * inv;
            v.y = o[mt][nt][1] * inv;
            v.z = o[mt][nt][2] * inv;
            v.w = o[mt][nt][3] * inv;
            *(float4*)(op + nt * 16 + quad * 4) = v;
        }
    }
}

extern "C" void kernel_launch(void* const* d_in, const int* in_sizes, int n_in,
                              void* d_out, int out_size, void* d_ws, size_t ws_size,
                              hipStream_t stream) {
    const float* x  = (const float*)d_in[0];
    const float* Wq = (const float*)d_in[1];
    const float* Wk = (const float*)d_in[2];
    const float* Wv = (const float*)d_in[3];
    float* outp = (float*)d_out;

    // workspace: [0, 50331648) qkvb bf16 (q,k row-major; v transposed)
    //            [50331648, 67108864) xb bf16; [67108864, 73400320) WbT bf16
    unsigned short* qkvb = (unsigned short*)d_ws;
    unsigned short* xb   = (unsigned short*)((char*)d_ws + 50331648);
    unsigned short* WbT  = (unsigned short*)((char*)d_ws + 67108864);

    convert_xw<<<dim3(8192 + 768), 256, 0, stream>>>(x, Wq, Wk, Wv, xb, WbT);
    qkv_gemm<<<dim3(B * S / 128, 3 * H * DH / 128), 256, 0, stream>>>(xb, WbT, qkvb);
    attn_mfma<<<dim3(S / 128, BH), 256, 0, stream>>>(qkvb, outp);
}